// Round 3
// baseline (151.978 us; speedup 1.0000x reference)
//
#include <hip/hip_runtime.h>
#include <math.h>

#define N_NODES 8192
#define EDGES   262144
#define D       256
#define ROWCAP  128   // raw in-degree cap (Binomial mean 32, 17-sigma safe)
#define PITCH   68    // LDS pitch: mult of 4 (b128 align), ==4 mod 32 (bank spread)

// ---------------- workspace layout (bytes) ----------------
// 0        : fill    32768     (int per row: raw in-edge count)      } one
// 32768    : s_src   32768     (fp32, atomicAdd-accumulated)         } 96KB
// 65536    : s_dst   32768     (fp32, atomicAdd-accumulated)         } memset
// 98304    : csr     4194304   (ROWCAP ints per row)
// 4292608  : h       8388608   (N x D fp32)
// total 12681216 bytes (~12.1 MB)

// -------- h = x @ W^T (fp32, no fp32 MFMA on CDNA4) + fused s_src/s_dst --------
__global__ __launch_bounds__(256)
void gemm_h(const float* __restrict__ x, const float* __restrict__ W,
            const float* __restrict__ a_src, const float* __restrict__ a_dst,
            float* __restrict__ h, float* __restrict__ s_src,
            float* __restrict__ s_dst) {
  __shared__ float As[32][PITCH];   // [k][m] K-major -> b128 fragment reads
  __shared__ float Bs[32][PITCH];   // [k][n]
  const int bm = blockIdx.x * 64;
  const int bj = blockIdx.y * 64;
  const int tid = threadIdx.x;
  const int tr = tid >> 4, tc = tid & 15;
  float acc[4][4] = {{0.f}};
  for (int k0 = 0; k0 < D; k0 += 32) {
#pragma unroll
    for (int f = 0; f < 2; ++f) {
      int idx = tid + f * 256;                 // 0..511
      int r = idx >> 3, c4 = (idx & 7) << 2;   // r 0..63, c4 0,4,..,28
      float4 va = *reinterpret_cast<const float4*>(&x[(size_t)(bm + r) * D + k0 + c4]);
      As[c4][r] = va.x; As[c4 + 1][r] = va.y; As[c4 + 2][r] = va.z; As[c4 + 3][r] = va.w;
      float4 vb = *reinterpret_cast<const float4*>(&W[(size_t)(bj + r) * D + k0 + c4]);
      Bs[c4][r] = vb.x; Bs[c4 + 1][r] = vb.y; Bs[c4 + 2][r] = vb.z; Bs[c4 + 3][r] = vb.w;
    }
    __syncthreads();
#pragma unroll
    for (int k = 0; k < 32; ++k) {
      float4 a4 = *reinterpret_cast<const float4*>(&As[k][tr * 4]);
      float4 b4 = *reinterpret_cast<const float4*>(&Bs[k][tc * 4]);
      float a[4] = {a4.x, a4.y, a4.z, a4.w};
      float b[4] = {b4.x, b4.y, b4.z, b4.w};
#pragma unroll
      for (int i = 0; i < 4; ++i)
#pragma unroll
        for (int j = 0; j < 4; ++j)
          acc[i][j] = fmaf(a[i], b[j], acc[i][j]);
    }
    __syncthreads();
  }
  // epilogue: store h tile + fused partial dots with a_src/a_dst
  float4 asv = *reinterpret_cast<const float4*>(&a_src[bj + tc * 4]);
  float4 adv = *reinterpret_cast<const float4*>(&a_dst[bj + tc * 4]);
#pragma unroll
  for (int i = 0; i < 4; ++i) {
    float4 v = make_float4(acc[i][0], acc[i][1], acc[i][2], acc[i][3]);
    *reinterpret_cast<float4*>(&h[(size_t)(bm + tr * 4 + i) * D + bj + tc * 4]) = v;
    float ps = v.x * asv.x + v.y * asv.y + v.z * asv.z + v.w * asv.w;
    float pd = v.x * adv.x + v.y * adv.y + v.z * adv.z + v.w * adv.w;
#pragma unroll
    for (int off = 8; off; off >>= 1) {
      ps += __shfl_down(ps, off, 16);   // reduce across the 16 tc lanes
      pd += __shfl_down(pd, off, 16);
    }
    if (tc == 0) {
      atomicAdd(&s_src[bm + tr * 4 + i], ps);
      atomicAdd(&s_dst[bm + tr * 4 + i], pd);
    }
  }
}

// -------- scatter raw edges into per-dst buckets (no dedup here) --------
// int64-vs-int32 detection inlined: int64 payload < 2^31 -> all odd 32-bit
// words of the first 64 entries are zero; int32 payload -> random node ids.
__global__ __launch_bounds__(256)
void scatter_kernel(const int* __restrict__ ei, int* __restrict__ fill,
                    int* __restrict__ csr) {
  int lane = threadIdx.x & 63;
  unsigned long long b = __ballot(ei[lane * 2 + 1] == 0);
  int is64 = (b == 0xFFFFFFFFFFFFFFFFull) ? 1 : 0;
  int e = blockIdx.x * 256 + threadIdx.x;   // grid exactly covers EDGES
  int src, dst;
  if (is64) { src = ei[2 * e];  dst = ei[2 * (EDGES + e)]; }
  else      { src = ei[e];      dst = ei[EDGES + e]; }
  int p = atomicAdd(&fill[dst], 1);
  if (p < ROWCAP) csr[dst * ROWCAP + p] = src;
}

// -------- per-row: dedup -> softmax -> SpMM -> ELU+res -> LayerNorm --------
__global__ __launch_bounds__(256)
void row_fused(const float* __restrict__ h, const float* __restrict__ s_src,
               const float* __restrict__ s_dst, const int* __restrict__ fill,
               const int* __restrict__ csr, const float* __restrict__ gamma,
               const float* __restrict__ beta, float* __restrict__ out) {
  __shared__ int   s_idx[ROWCAP];
  __shared__ float s_w[ROWCAP];
  __shared__ float red[8];
  const int row  = blockIdx.x;
  const int tid  = threadIdx.x;
  const int lane = tid & 63, wid = tid >> 6;
  int len = fill[row];
  if (len > ROWCAP) len = ROWCAP;
  const float sd = s_dst[row];

  // stage raw indices
  for (int i = tid; i < len; i += 256) s_idx[i] = csr[row * ROWCAP + i];
  __syncthreads();

  // logits; duplicates (keep-first) and exact-zero logits get -3e38 sentinel
  // (reference: duplicate (dst,src) writes carry identical e; (attn==0) mask)
  float lmax = -3.0e38f;
  for (int i = tid; i < len; i += 256) {
    int s = s_idx[i];
    bool dup = false;
    for (int j = 0; j < i; ++j)
      if (s_idx[j] == s) { dup = true; break; }
    float v;
    if (dup) {
      v = -3.0e38f;
    } else {
      v = s_src[s] + sd;
      v = (v >= 0.f) ? v : 0.2f * v;      // leaky_relu 0.2
      if (v == 0.0f) v = -3.0e38f;        // (attn == 0) * -1e9 mask
    }
    s_w[i] = v;
    lmax = fmaxf(lmax, v);
  }
#pragma unroll
  for (int off = 32; off; off >>= 1) lmax = fmaxf(lmax, __shfl_down(lmax, off, 64));
  if (lane == 0) red[wid] = lmax;
  __syncthreads();
  lmax = fmaxf(fmaxf(red[0], red[1]), fmaxf(red[2], red[3]));

  float lsum = 0.f;
  for (int i = tid; i < len; i += 256) {
    float e = expf(s_w[i] - lmax);        // sentinel -> exp(-huge) = 0
    s_w[i] = e;
    lsum += e;
  }
#pragma unroll
  for (int off = 32; off; off >>= 1) lsum += __shfl_down(lsum, off, 64);
  if (lane == 0) red[4 + wid] = lsum;
  __syncthreads();
  lsum = red[4] + red[5] + red[6] + red[7];
  float inv = 1.0f / lsum;
  for (int i = tid; i < len; i += 256) {
    float w = s_w[i] * inv;
    s_w[i] = (w > 1e-6f) ? w : 0.f;       // attn * (attn > 1e-6)
  }
  __syncthreads();

  // SpMM: thread owns one column; w=0 entries contribute nothing
  float acc = 0.f;
#pragma unroll 4
  for (int i = 0; i < len; ++i)
    acc += s_w[i] * h[(size_t)s_idx[i] * D + tid];

  float z = ((acc > 0.f) ? acc : expm1f(acc)) + h[(size_t)row * D + tid];

  // LayerNorm (biased var, eps 1e-5)
  float v1 = z;
#pragma unroll
  for (int off = 32; off; off >>= 1) v1 += __shfl_down(v1, off, 64);
  if (lane == 0) red[wid] = v1;
  __syncthreads();
  float mean = (red[0] + red[1] + red[2] + red[3]) * (1.0f / 256.0f);
  __syncthreads();
  float d = z - mean;
  float v2 = d * d;
#pragma unroll
  for (int off = 32; off; off >>= 1) v2 += __shfl_down(v2, off, 64);
  if (lane == 0) red[wid] = v2;
  __syncthreads();
  float var = (red[0] + red[1] + red[2] + red[3]) * (1.0f / 256.0f);
  out[(size_t)row * D + tid] = gamma[tid] * d * rsqrtf(var + 1e-5f) + beta[tid];
}

extern "C" void kernel_launch(void* const* d_in, const int* in_sizes, int n_in,
                              void* d_out, int out_size, void* d_ws, size_t ws_size,
                              hipStream_t stream) {
  const float* x     = (const float*)d_in[0];
  const int*   ei    = (const int*)d_in[1];
  const float* W     = (const float*)d_in[2];
  const float* a_src = (const float*)d_in[3];
  const float* a_dst = (const float*)d_in[4];
  const float* gamma = (const float*)d_in[5];
  const float* beta  = (const float*)d_in[6];
  float* out = (float*)d_out;

  char* ws = (char*)d_ws;
  int*   fill   = (int*)(ws);
  float* s_src  = (float*)(ws + 32768);
  float* s_dst  = (float*)(ws + 65536);
  int*   csr    = (int*)(ws + 98304);
  float* h      = (float*)(ws + 4292608);
  if (ws_size < 12681216) return;  // workspace too small (not expected)

  // zero fill + s_src + s_dst in one contiguous memset (96 KB)
  hipMemsetAsync(ws, 0, 98304, stream);
  gemm_h<<<dim3(N_NODES / 64, D / 64), 256, 0, stream>>>(x, W, a_src, a_dst,
                                                         h, s_src, s_dst);
  scatter_kernel<<<EDGES / 256, 256, 0, stream>>>(ei, fill, csr);
  row_fused<<<N_NODES, 256, 0, stream>>>(h, s_src, s_dst, fill, csr, gamma, beta, out);
}

// Round 4
// 137.941 us; speedup vs baseline: 1.1018x; 1.1018x over previous
//
#include <hip/hip_runtime.h>
#include <math.h>

#define N_NODES 8192
#define EDGES   262144
#define D       256
#define ROWCAP  128   // raw in-degree cap (Binomial mean 32, 17-sigma safe)
#define PITCH   68    // LDS pitch: mult of 4 (b128 align), ==4 mod 32 (bank spread)

// ---------------- workspace layout (bytes) ----------------
// 0        : fill    32768     (int per row: raw in-edge count)      } one
// 32768    : s_src   32768     (fp32, atomicAdd-accumulated)         } 96KB
// 65536    : s_dst   32768     (fp32, atomicAdd-accumulated)         } memset
// 98304    : csr     4194304   (ROWCAP ints per row)
// 4292608  : h       8388608   (N x D fp32)
// total 12681216 bytes (~12.1 MB)

// -------- h = x @ W^T (fp32, no fp32 MFMA on CDNA4) + fused s_src/s_dst --------
__global__ __launch_bounds__(256)
void gemm_h(const float* __restrict__ x, const float* __restrict__ W,
            const float* __restrict__ a_src, const float* __restrict__ a_dst,
            float* __restrict__ h, float* __restrict__ s_src,
            float* __restrict__ s_dst) {
  __shared__ float As[32][PITCH];   // [k][m] K-major -> b128 fragment reads
  __shared__ float Bs[32][PITCH];   // [k][n]
  const int bm = blockIdx.x * 64;
  const int bj = blockIdx.y * 64;
  const int tid = threadIdx.x;
  const int tr = tid >> 4, tc = tid & 15;
  float acc[4][4] = {{0.f}};
  for (int k0 = 0; k0 < D; k0 += 32) {
#pragma unroll
    for (int f = 0; f < 2; ++f) {
      int idx = tid + f * 256;                 // 0..511
      int r = idx >> 3, c4 = (idx & 7) << 2;   // r 0..63, c4 0,4,..,28
      float4 va = *reinterpret_cast<const float4*>(&x[(size_t)(bm + r) * D + k0 + c4]);
      As[c4][r] = va.x; As[c4 + 1][r] = va.y; As[c4 + 2][r] = va.z; As[c4 + 3][r] = va.w;
      float4 vb = *reinterpret_cast<const float4*>(&W[(size_t)(bj + r) * D + k0 + c4]);
      Bs[c4][r] = vb.x; Bs[c4 + 1][r] = vb.y; Bs[c4 + 2][r] = vb.z; Bs[c4 + 3][r] = vb.w;
    }
    __syncthreads();
#pragma unroll
    for (int k = 0; k < 32; ++k) {
      float4 a4 = *reinterpret_cast<const float4*>(&As[k][tr * 4]);
      float4 b4 = *reinterpret_cast<const float4*>(&Bs[k][tc * 4]);
      float a[4] = {a4.x, a4.y, a4.z, a4.w};
      float b[4] = {b4.x, b4.y, b4.z, b4.w};
#pragma unroll
      for (int i = 0; i < 4; ++i)
#pragma unroll
        for (int j = 0; j < 4; ++j)
          acc[i][j] = fmaf(a[i], b[j], acc[i][j]);
    }
    __syncthreads();
  }
  // epilogue: store h tile + fused partial dots with a_src/a_dst
  float4 asv = *reinterpret_cast<const float4*>(&a_src[bj + tc * 4]);
  float4 adv = *reinterpret_cast<const float4*>(&a_dst[bj + tc * 4]);
#pragma unroll
  for (int i = 0; i < 4; ++i) {
    float4 v = make_float4(acc[i][0], acc[i][1], acc[i][2], acc[i][3]);
    *reinterpret_cast<float4*>(&h[(size_t)(bm + tr * 4 + i) * D + bj + tc * 4]) = v;
    float ps = v.x * asv.x + v.y * asv.y + v.z * asv.z + v.w * asv.w;
    float pd = v.x * adv.x + v.y * adv.y + v.z * adv.z + v.w * adv.w;
#pragma unroll
    for (int off = 8; off; off >>= 1) {
      ps += __shfl_down(ps, off, 16);   // reduce across the 16 tc lanes
      pd += __shfl_down(pd, off, 16);
    }
    if (tc == 0) {
      atomicAdd(&s_src[bm + tr * 4 + i], ps);
      atomicAdd(&s_dst[bm + tr * 4 + i], pd);
    }
  }
}

// -------- scatter raw edges into per-dst buckets (no dedup here) --------
__global__ __launch_bounds__(256)
void scatter_kernel(const int* __restrict__ ei, int* __restrict__ fill,
                    int* __restrict__ csr) {
  int lane = threadIdx.x & 63;
  unsigned long long b = __ballot(ei[lane * 2 + 1] == 0);
  int is64 = (b == 0xFFFFFFFFFFFFFFFFull) ? 1 : 0;
  int e = blockIdx.x * 256 + threadIdx.x;   // grid exactly covers EDGES
  int src, dst;
  if (is64) { src = ei[2 * e];  dst = ei[2 * (EDGES + e)]; }
  else      { src = ei[e];      dst = ei[EDGES + e]; }
  int p = atomicAdd(&fill[dst], 1);
  if (p < ROWCAP) csr[dst * ROWCAP + p] = src;
}

// -------- per-row (one WAVE per row): dedup -> softmax -> SpMM -> ELU+res -> LN --------
__global__ __launch_bounds__(256)
void row_fused(const float* __restrict__ h, const float* __restrict__ s_src,
               const float* __restrict__ s_dst, const int* __restrict__ fill,
               const int* __restrict__ csr, const float* __restrict__ gamma,
               const float* __restrict__ beta, float* __restrict__ out) {
  __shared__ int   s_idx[4][ROWCAP];
  __shared__ float s_w[4][ROWCAP];
  const int w    = threadIdx.x >> 6;       // wave id 0..3
  const int lane = threadIdx.x & 63;
  const int row  = blockIdx.x * 4 + w;
  int len = fill[row];
  if (len > ROWCAP) len = ROWCAP;
  const int len_pad = (len + 3) & ~3;
  const float sd = s_dst[row];

  // stage raw src indices (lane-parallel)
  for (int i = lane; i < len; i += 64) s_idx[w][i] = csr[row * ROWCAP + i];
  __syncthreads();   // s_idx visible for cross-lane dup scan

  // logits; duplicates (keep-first) and exact-zero logits get -3e38 sentinel
  float lmax = -3.0e38f;
  for (int i = lane; i < len; i += 64) {
    int s = s_idx[w][i];
    bool dup = false;
    for (int j = 0; j < i; ++j)
      if (s_idx[w][j] == s) { dup = true; break; }
    float v;
    if (dup) {
      v = -3.0e38f;
    } else {
      v = s_src[s] + sd;
      v = (v >= 0.f) ? v : 0.2f * v;      // leaky_relu 0.2
      if (v == 0.0f) v = -3.0e38f;        // (attn == 0) * -1e9 mask
    }
    s_w[w][i] = v;
    lmax = fmaxf(lmax, v);
  }
#pragma unroll
  for (int off = 32; off; off >>= 1) lmax = fmaxf(lmax, __shfl_xor(lmax, off, 64));

  float lsum = 0.f;
  for (int i = lane; i < len; i += 64) {
    float e = expf(s_w[w][i] - lmax);     // sentinel -> 0
    s_w[w][i] = e;
    lsum += e;
  }
#pragma unroll
  for (int off = 32; off; off >>= 1) lsum += __shfl_xor(lsum, off, 64);
  float inv = (lsum > 0.f) ? (1.0f / lsum) : 0.f;
  for (int i = lane; i < len; i += 64) {
    float ww = s_w[w][i] * inv;
    s_w[w][i] = (ww > 1e-6f) ? ww : 0.f;  // attn * (attn > 1e-6)
  }
  // zero-pad to multiple of 4 (kills SpMM tail)
  for (int i = len + lane; i < len_pad; i += 64) { s_w[w][i] = 0.f; s_idx[w][i] = 0; }
  __syncthreads();   // s_w/s_idx visible for cross-lane SpMM reads

  // SpMM: lane owns 4 columns (float4); 4 independent gathers in flight
  float4 acc = make_float4(0.f, 0.f, 0.f, 0.f);
  for (int i = 0; i < len_pad; i += 4) {
    float w0 = s_w[w][i], w1 = s_w[w][i + 1], w2 = s_w[w][i + 2], w3 = s_w[w][i + 3];
    const float4 h0 = *reinterpret_cast<const float4*>(&h[(size_t)s_idx[w][i]     * D + lane * 4]);
    const float4 h1 = *reinterpret_cast<const float4*>(&h[(size_t)s_idx[w][i + 1] * D + lane * 4]);
    const float4 h2 = *reinterpret_cast<const float4*>(&h[(size_t)s_idx[w][i + 2] * D + lane * 4]);
    const float4 h3 = *reinterpret_cast<const float4*>(&h[(size_t)s_idx[w][i + 3] * D + lane * 4]);
    acc.x = fmaf(w0, h0.x, fmaf(w1, h1.x, fmaf(w2, h2.x, fmaf(w3, h3.x, acc.x))));
    acc.y = fmaf(w0, h0.y, fmaf(w1, h1.y, fmaf(w2, h2.y, fmaf(w3, h3.y, acc.y))));
    acc.z = fmaf(w0, h0.z, fmaf(w1, h1.z, fmaf(w2, h2.z, fmaf(w3, h3.z, acc.z))));
    acc.w = fmaf(w0, h0.w, fmaf(w1, h1.w, fmaf(w2, h2.w, fmaf(w3, h3.w, acc.w))));
  }

  // ELU + residual
  const float4 hr = *reinterpret_cast<const float4*>(&h[(size_t)row * D + lane * 4]);
  float4 z;
  z.x = ((acc.x > 0.f) ? acc.x : expm1f(acc.x)) + hr.x;
  z.y = ((acc.y > 0.f) ? acc.y : expm1f(acc.y)) + hr.y;
  z.z = ((acc.z > 0.f) ? acc.z : expm1f(acc.z)) + hr.z;
  z.w = ((acc.w > 0.f) ? acc.w : expm1f(acc.w)) + hr.w;

  // LayerNorm over 256 cols within the wave (biased var, eps 1e-5)
  float s1 = z.x + z.y + z.z + z.w;
#pragma unroll
  for (int off = 32; off; off >>= 1) s1 += __shfl_xor(s1, off, 64);
  float mean = s1 * (1.0f / 256.0f);
  float dx = z.x - mean, dy = z.y - mean, dz = z.z - mean, dw = z.w - mean;
  float s2 = dx * dx + dy * dy + dz * dz + dw * dw;
#pragma unroll
  for (int off = 32; off; off >>= 1) s2 += __shfl_xor(s2, off, 64);
  float rs = rsqrtf(s2 * (1.0f / 256.0f) + 1e-5f);

  const float4 gm = *reinterpret_cast<const float4*>(&gamma[lane * 4]);
  const float4 bt = *reinterpret_cast<const float4*>(&beta[lane * 4]);
  float4 o;
  o.x = gm.x * dx * rs + bt.x;
  o.y = gm.y * dy * rs + bt.y;
  o.z = gm.z * dz * rs + bt.z;
  o.w = gm.w * dw * rs + bt.w;
  *reinterpret_cast<float4*>(&out[(size_t)row * D + lane * 4]) = o;
}

extern "C" void kernel_launch(void* const* d_in, const int* in_sizes, int n_in,
                              void* d_out, int out_size, void* d_ws, size_t ws_size,
                              hipStream_t stream) {
  const float* x     = (const float*)d_in[0];
  const int*   ei    = (const int*)d_in[1];
  const float* W     = (const float*)d_in[2];
  const float* a_src = (const float*)d_in[3];
  const float* a_dst = (const float*)d_in[4];
  const float* gamma = (const float*)d_in[5];
  const float* beta  = (const float*)d_in[6];
  float* out = (float*)d_out;

  char* ws = (char*)d_ws;
  int*   fill   = (int*)(ws);
  float* s_src  = (float*)(ws + 32768);
  float* s_dst  = (float*)(ws + 65536);
  int*   csr    = (int*)(ws + 98304);
  float* h      = (float*)(ws + 4292608);
  if (ws_size < 12681216) return;  // workspace too small (not expected)

  // zero fill + s_src + s_dst in one contiguous memset (96 KB)
  hipMemsetAsync(ws, 0, 98304, stream);
  gemm_h<<<dim3(N_NODES / 64, D / 64), 256, 0, stream>>>(x, W, a_src, a_dst,
                                                         h, s_src, s_dst);
  scatter_kernel<<<EDGES / 256, 256, 0, stream>>>(ei, fill, csr);
  row_fused<<<N_NODES / 4, 256, 0, stream>>>(h, s_src, s_dst, fill, csr, gamma, beta, out);
}